// Round 10
// baseline (144.893 us; speedup 1.0000x reference)
//
#include <hip/hip_runtime.h>
#include <hip/hip_bf16.h>

// Problem constants (fixed by setup_inputs)
#define N_NODES  50000
#define D_NODE   128
#define E_TOTAL  600000
#define IN_FEAT  256      // 2 * d_node
#define OUT_FEAT 128
#define ALPHA_OFF (600000 * 128)   // fits in int32 (77.4M)
#define NB       64       // src buckets (782 nodes = 391 KB Z slice, fits XCD L2)
#define HBLK     1024     // hist/scatter block size
#define NHB      586      // ceil(600000/1024)
#define SLOTS    9750     // edge-slots per XCD group (75000 mean + huge margin)

typedef __bf16 bf16x8 __attribute__((ext_vector_type(8)));
typedef __bf16 bf16x4 __attribute__((ext_vector_type(4)));
typedef float  f32x4  __attribute__((ext_vector_type(4)));

__device__ __forceinline__ int bucket_of(int node) { return node / 782; }          // 0..63
__device__ __forceinline__ int sortbin_of(int b)   { return ((b & 7) << 3) | (b >> 3); }
// sortbin groups buckets by (b&7) -> XCD group g = sb>>3; group g processed by
// blocks with blockIdx%8 == g (hardware round-robins blockIdx across 8 XCDs).

// ================= FAST PATH =================
// sigmoid(W.[nf_src|nf_dst]) = sigmoid(zs[src] + zd[dst]), Z bf16 [50000][256].
// R6: nt on partial-line stores = 1.7x write amp. R9: nt on full-line 1KB wave
// stores works (109us). R10: src-bucket sort + XCD pinning -> zs reads L2-local.

// ---- prep: Wcat -> per-fragment-swizzled bf16 ----
__global__ void convert_wcat(const float* __restrict__ W, __bf16* __restrict__ wl) {
    int gid  = blockIdx.x * 256 + threadIdx.x;   // 0..4095
    int lane = gid & 63;
    int nk   = gid >> 6;
    int n    = nk & 15;
    int kk   = nk >> 4;
    int o2   = n * 16 + (lane & 15);
    int k2   = kk * 32 + (lane >> 4) * 8;
    const float* src = (o2 < 128) ? (W + o2 * IN_FEAT + k2)
                                  : (W + (o2 - 128) * IN_FEAT + 128 + k2);
    bf16x8 h;
    #pragma unroll
    for (int j = 0; j < 8; ++j) h[j] = (__bf16)src[j];
    *(bf16x8*)(wl + gid * 8) = h;
}

// ---- node projection: Z[v][o2] = sum_k n_f[v][k] * Wcat[o2][k] ----
__launch_bounds__(64)
__global__ void zgemm(const float* __restrict__ n_f,
                      const __bf16* __restrict__ wl,
                      __bf16* __restrict__ Z) {
    const int lane = threadIdx.x;
    const int v0   = blockIdx.x * 16;
    const int lr   = lane & 15;
    const int lg   = lane >> 4;

    f32x4 acc[16];
    #pragma unroll
    for (int n = 0; n < 16; ++n) acc[n] = (f32x4){0.f, 0.f, 0.f, 0.f};

    #pragma unroll
    for (int kk = 0; kk < 4; ++kk) {
        const float* ap = n_f + (v0 + lr) * D_NODE + kk * 32 + lg * 8;
        float4 v0f = *(const float4*)ap;
        float4 v1f = *(const float4*)(ap + 4);
        bf16x8 a;
        a[0] = (__bf16)v0f.x; a[1] = (__bf16)v0f.y;
        a[2] = (__bf16)v0f.z; a[3] = (__bf16)v0f.w;
        a[4] = (__bf16)v1f.x; a[5] = (__bf16)v1f.y;
        a[6] = (__bf16)v1f.z; a[7] = (__bf16)v1f.w;
        const bf16x8* bp = (const bf16x8*)(wl) + kk * 16 * 64 + lane;
        #pragma unroll
        for (int n = 0; n < 16; ++n) {
            bf16x8 b = bp[n * 64];
            acc[n] = __builtin_amdgcn_mfma_f32_16x16x32_bf16(a, b, acc[n], 0, 0, 0);
        }
    }
    #pragma unroll
    for (int n = 0; n < 16; ++n) {
        const int col = n * 16 + lr;
        #pragma unroll
        for (int j = 0; j < 4; ++j)
            Z[(v0 + lg * 4 + j) * 256 + col] = (__bf16)acc[n][j];
    }
}

// ---- sort: deterministic-output counting sort of edge ids into 64 sortbins ----
__global__ void k_init(int* __restrict__ hist) {
    if (threadIdx.x < NB) hist[threadIdx.x] = 0;
}

__global__ void k_hist(const int* __restrict__ src, int* __restrict__ hist) {
    __shared__ int cnt[NB];
    const int t = threadIdx.x;
    if (t < NB) cnt[t] = 0;
    __syncthreads();
    const int e = blockIdx.x * HBLK + t;
    if (e < E_TOTAL) atomicAdd(&cnt[sortbin_of(bucket_of(src[e]))], 1);
    __syncthreads();
    if (t < NB && cnt[t] > 0) atomicAdd(&hist[t], cnt[t]);
}

__global__ void k_scan(const int* __restrict__ hist, int* __restrict__ cursor,
                       int* __restrict__ xbase) {
    __shared__ int h[NB];
    const int t = threadIdx.x;
    if (t < NB) h[t] = hist[t];
    __syncthreads();
    if (t == 0) {
        int run = 0;
        for (int sb = 0; sb < NB; ++sb) {
            if ((sb & 7) == 0) xbase[sb >> 3] = run;
            cursor[sb] = run;
            run += h[sb];
        }
        xbase[8] = run;   // == E_TOTAL
    }
}

__global__ void k_scatter(const int* __restrict__ src, int* __restrict__ perm,
                          int* __restrict__ cursor) {
    __shared__ int cnt[NB];
    __shared__ int base[NB];
    const int t = threadIdx.x;
    if (t < NB) cnt[t] = 0;
    __syncthreads();
    const int e = blockIdx.x * HBLK + t;
    int sb = 0, lofs = 0;
    if (e < E_TOTAL) {
        sb = sortbin_of(bucket_of(src[e]));
        lofs = atomicAdd(&cnt[sb], 1);
    }
    __syncthreads();
    if (t < NB) base[t] = (cnt[t] > 0) ? atomicAdd(&cursor[t], cnt[t]) : 0;
    __syncthreads();
    if (e < E_TOTAL) perm[base[sb] + lofs] = e;
}

// ---- edge apply, bucketed: block j -> XCD group j&7 -> contiguous perm range.
// 32 lanes/edge, 8 edges/block; zs reads hit the XCD-local L2 slice.
__launch_bounds__(256)
__global__ void edge_apply_b(const __bf16* __restrict__ Z,
                             const int* __restrict__ src_idx,
                             const int* __restrict__ dst_idx,
                             const int* __restrict__ perm,
                             const int* __restrict__ xbase,
                             float* __restrict__ out) {
    const int j  = blockIdx.x;
    const int x  = j & 7;
    const int s  = j >> 3;
    const int t  = threadIdx.x;
    const int le = t >> 5;             // local edge 0..7
    const int c4 = (t & 31) * 4;

    const int pos = xbase[x] + s * 8 + le;
    if (pos >= xbase[x + 1]) return;
    const int e  = perm[pos];

    const int sv = src_idx[e];
    const int dv = dst_idx[e];

    if ((t & 31) == 0) out[ALPHA_OFF + e] = 1.0f;  // softmax(size-1) == 1

    bf16x4 zs = *(const bf16x4*)(Z + sv * 256 + c4);
    bf16x4 zd = *(const bf16x4*)(Z + dv * 256 + 128 + c4);

    f32x4 r;
    #pragma unroll
    for (int q = 0; q < 4; ++q) {
        float xx = (float)zs[q] + (float)zd[q];
        r[q] = __builtin_amdgcn_rcpf(1.0f + __expf(-xx));
    }
    __builtin_nontemporal_store(r, (f32x4*)(out + e * OUT_FEAT + c4));
}

// ---- R9 edge apply (mid fallback, no sort) ----
__launch_bounds__(256)
__global__ void edge_apply(const __bf16* __restrict__ Z,
                           const int* __restrict__ src_idx,
                           const int* __restrict__ dst_idx,
                           float* __restrict__ out) {
    const int t  = blockIdx.x * 256 + threadIdx.x;
    const int e  = t >> 5;
    const int c4 = (t & 31) * 4;
    const int sv = src_idx[e];
    const int dv = dst_idx[e];
    if ((t & 31) == 0) out[ALPHA_OFF + e] = 1.0f;
    bf16x4 zs = *(const bf16x4*)(Z + sv * 256 + c4);
    bf16x4 zd = *(const bf16x4*)(Z + dv * 256 + 128 + c4);
    f32x4 r;
    #pragma unroll
    for (int q = 0; q < 4; ++q) {
        float xx = (float)zs[q] + (float)zd[q];
        r[q] = __builtin_amdgcn_rcpf(1.0f + __expf(-xx));
    }
    __builtin_nontemporal_store(r, (f32x4*)(out + e * OUT_FEAT + c4));
}

// ================= FALLBACK PATH (R3, needs only 64 KB ws) =================
__global__ void convert_w_fb(const float* __restrict__ W, __bf16* __restrict__ wl) {
    int gid = blockIdx.x * 256 + threadIdx.x;
    int lane = gid & 63;
    int nk   = gid >> 6;
    int n    = nk & 7;
    int kk   = nk >> 3;
    int row  = n * 16 + (lane & 15);
    int col  = kk * 32 + (lane >> 4) * 8;
    const float* src = W + row * IN_FEAT + col;
    bf16x8 h;
    #pragma unroll
    for (int j = 0; j < 8; ++j) h[j] = (__bf16)src[j];
    *(bf16x8*)(wl + gid * 8) = h;
}

__launch_bounds__(64, 2)
__global__ void edge_kernel_fb(const float* __restrict__ n_f,
                               const __bf16* __restrict__ wl,
                               const int*   __restrict__ src_idx,
                               const int*   __restrict__ dst_idx,
                               float* __restrict__ out) {
    const int lane = threadIdx.x;
    const int e0   = blockIdx.x * 64;
    const int lr   = lane & 15;
    const int lg   = lane >> 4;

    out[ALPHA_OFF + e0 + lane] = 1.0f;

    int sn[4], dn[4];
    #pragma unroll
    for (int r = 0; r < 4; ++r) {
        const int e = e0 + r * 16 + lr;
        sn[r] = src_idx[e];
        dn[r] = dst_idx[e];
    }
    f32x4 acc[4][8];
    #pragma unroll
    for (int r = 0; r < 4; ++r)
        #pragma unroll
        for (int n = 0; n < 8; ++n) acc[r][n] = (f32x4){0.f, 0.f, 0.f, 0.f};

    #pragma unroll
    for (int kk = 0; kk < 8; ++kk) {
        bf16x8 a[4];
        #pragma unroll
        for (int r = 0; r < 4; ++r) {
            const int node = (kk < 4) ? sn[r] : dn[r];
            const float* ap = n_f + node * D_NODE + (kk & 3) * 32 + lg * 8;
            float4 u0 = *(const float4*)ap;
            float4 u1 = *(const float4*)(ap + 4);
            a[r][0] = (__bf16)u0.x; a[r][1] = (__bf16)u0.y;
            a[r][2] = (__bf16)u0.z; a[r][3] = (__bf16)u0.w;
            a[r][4] = (__bf16)u1.x; a[r][5] = (__bf16)u1.y;
            a[r][6] = (__bf16)u1.z; a[r][7] = (__bf16)u1.w;
        }
        const bf16x8* bp = (const bf16x8*)(wl) + kk * 8 * 64 + lane;
        #pragma unroll
        for (int n = 0; n < 8; ++n) {
            bf16x8 b = bp[n * 64];
            #pragma unroll
            for (int r = 0; r < 4; ++r)
                acc[r][n] = __builtin_amdgcn_mfma_f32_16x16x32_bf16(a[r], b, acc[r][n], 0, 0, 0);
        }
    }
    #pragma unroll
    for (int r = 0; r < 4; ++r) {
        const int ebase = e0 + r * 16 + lg * 4;
        #pragma unroll
        for (int n = 0; n < 8; ++n) {
            const int col = n * 16 + lr;
            #pragma unroll
            for (int j = 0; j < 4; ++j) {
                float xx = acc[r][n][j];
                out[(ebase + j) * OUT_FEAT + col] = __builtin_amdgcn_rcpf(1.0f + __expf(-xx));
            }
        }
    }
}

extern "C" void kernel_launch(void* const* d_in, const int* in_sizes, int n_in,
                              void* d_out, int out_size, void* d_ws, size_t ws_size,
                              hipStream_t stream) {
    const float* n_f    = (const float*)d_in[0];
    const float* W_edge = (const float*)d_in[1];
    // d_in[2] = W_attn: mathematically dead (softmax over size-1 axis == 1)
    const int* src_idx  = (const int*)d_in[3];
    const int* dst_idx  = (const int*)d_in[4];
    float* out = (float*)d_out;

    // ws layout
    const size_t off_wl   = 0;                       // 65536 B
    const size_t off_Z    = 65536;                   // 25,600,000 B
    const size_t off_perm = off_Z + (size_t)N_NODES * 256 * 2;   // 2,400,000 B
    const size_t off_hist = off_perm + (size_t)E_TOTAL * 4;      // 256 B
    const size_t off_cur  = off_hist + NB * 4;                   // 256 B
    const size_t off_xb   = off_cur + NB * 4;                    // 36 B
    const size_t need_sort  = off_xb + 9 * 4;
    const size_t need_plain = off_perm;

    if (ws_size >= need_sort) {
        __bf16* wl   = (__bf16*)((char*)d_ws + off_wl);
        __bf16* Z    = (__bf16*)((char*)d_ws + off_Z);
        int* perm    = (int*)((char*)d_ws + off_perm);
        int* hist    = (int*)((char*)d_ws + off_hist);
        int* cursor  = (int*)((char*)d_ws + off_cur);
        int* xbase   = (int*)((char*)d_ws + off_xb);

        convert_wcat<<<16, 256, 0, stream>>>(W_edge, wl);
        zgemm<<<N_NODES / 16, 64, 0, stream>>>(n_f, wl, Z);
        k_init<<<1, 128, 0, stream>>>(hist);
        k_hist<<<NHB, HBLK, 0, stream>>>(src_idx, hist);
        k_scan<<<1, 64, 0, stream>>>(hist, cursor, xbase);
        k_scatter<<<NHB, HBLK, 0, stream>>>(src_idx, perm, cursor);
        edge_apply_b<<<SLOTS * 8, 256, 0, stream>>>(Z, src_idx, dst_idx, perm, xbase, out);
    } else if (ws_size >= need_plain) {
        __bf16* wl = (__bf16*)((char*)d_ws + off_wl);
        __bf16* Z  = (__bf16*)((char*)d_ws + off_Z);
        convert_wcat<<<16, 256, 0, stream>>>(W_edge, wl);
        zgemm<<<N_NODES / 16, 64, 0, stream>>>(n_f, wl, Z);
        edge_apply<<<(E_TOTAL * 32) / 256, 256, 0, stream>>>(Z, src_idx, dst_idx, out);
    } else {
        __bf16* wl = (__bf16*)d_ws;
        convert_w_fb<<<16, 256, 0, stream>>>(W_edge, wl);
        edge_kernel_fb<<<E_TOTAL / 64, 64, 0, stream>>>(n_f, wl, src_idx, dst_idx, out);
    }
}

// Round 11
// 109.170 us; speedup vs baseline: 1.3272x; 1.3272x over previous
//
#include <hip/hip_runtime.h>
#include <hip/hip_bf16.h>

// Problem constants (fixed by setup_inputs)
#define N_NODES  50000
#define D_NODE   128
#define E_TOTAL  600000
#define IN_FEAT  256      // 2 * d_node
#define OUT_FEAT 128
#define ALPHA_OFF (600000 * 128)   // fits in int32 (77.4M)

typedef __bf16 bf16x8 __attribute__((ext_vector_type(8)));
typedef __bf16 bf16x4 __attribute__((ext_vector_type(4)));
typedef float  f32x4  __attribute__((ext_vector_type(4)));

// ================= FAST PATH (R9 structure — best measured: 109.3 us) =====
// sigmoid(W.[nf_src|nf_dst]) = sigmoid(zs[src] + zd[dst]),
//   zs = n_f @ W[:, :128]^T,  zd = n_f @ W[:, 128:]^T  (per-node, reused ~12x)
// Z stored bf16 [N_NODES][256] (zs cols 0..127, zd cols 128..255) = 25.6 MB.
// R6 lesson: nt on partial-line stores = 1.7x write amplification. NEVER.
// R9 lesson: nt on full-line wave stores (1KB/instr) works: keeps the 310 MB
//   output stream out of L2/L3 so Z stays cache-resident (126.9 -> 109.3 us).
// R10 lesson: src-bucket sort + XCD pinning regresses (-35 us): sort atomics
//   + perm indirection + scattered alpha writes exceed the L2-locality gain.
// Fabric model: edge_apply moves ~620 MB in ~97 us = 6.4 TB/s, within ~8% of
// the 6.8-7.0 TB/s this chip's fill kernels achieve -> near structural floor.

// ---- prep: Wcat -> per-fragment-swizzled bf16 (for the node-projection GEMM) ----
// Wcat[o2][k2] = o2<128 ? W[o2][k2] : W[o2-128][128+k2]   (o2<256, k2<128)
// wl[(((kk*16 + n)*64) + lane)*8 + j] = Wcat[n*16 + (lane&15)][kk*32 + (lane>>4)*8 + j]
__global__ void convert_wcat(const float* __restrict__ W, __bf16* __restrict__ wl) {
    int gid  = blockIdx.x * 256 + threadIdx.x;   // 0..4095, one bf16x8 each
    int lane = gid & 63;
    int nk   = gid >> 6;        // 0..63
    int n    = nk & 15;         // 16 col-groups (N=256)
    int kk   = nk >> 4;         // 0..3       (K=128)
    int o2   = n * 16 + (lane & 15);
    int k2   = kk * 32 + (lane >> 4) * 8;
    const float* src = (o2 < 128) ? (W + o2 * IN_FEAT + k2)
                                  : (W + (o2 - 128) * IN_FEAT + 128 + k2);
    bf16x8 h;
    #pragma unroll
    for (int j = 0; j < 8; ++j) h[j] = (__bf16)src[j];
    *(bf16x8*)(wl + gid * 8) = h;
}

// ---- node projection: Z[v][o2] = sum_k n_f[v][k] * Wcat[o2][k] ----
// one wave = 16 nodes x 256 cols, K=128. 50000 = 3125 * 16 exact.
__launch_bounds__(64)
__global__ void zgemm(const float* __restrict__ n_f,
                      const __bf16* __restrict__ wl,
                      __bf16* __restrict__ Z) {
    const int lane = threadIdx.x;
    const int v0   = blockIdx.x * 16;
    const int lr   = lane & 15;
    const int lg   = lane >> 4;

    f32x4 acc[16];
    #pragma unroll
    for (int n = 0; n < 16; ++n) acc[n] = (f32x4){0.f, 0.f, 0.f, 0.f};

    #pragma unroll
    for (int kk = 0; kk < 4; ++kk) {               // K = 128 = 4 * 32
        const float* ap = n_f + (v0 + lr) * D_NODE + kk * 32 + lg * 8;
        float4 v0f = *(const float4*)ap;
        float4 v1f = *(const float4*)(ap + 4);
        bf16x8 a;
        a[0] = (__bf16)v0f.x; a[1] = (__bf16)v0f.y;
        a[2] = (__bf16)v0f.z; a[3] = (__bf16)v0f.w;
        a[4] = (__bf16)v1f.x; a[5] = (__bf16)v1f.y;
        a[6] = (__bf16)v1f.z; a[7] = (__bf16)v1f.w;
        const bf16x8* bp = (const bf16x8*)(wl) + kk * 16 * 64 + lane;
        #pragma unroll
        for (int n = 0; n < 16; ++n) {             // N = 256 = 16 * 16
            bf16x8 b = bp[n * 64];
            acc[n] = __builtin_amdgcn_mfma_f32_16x16x32_bf16(a, b, acc[n], 0, 0, 0);
        }
    }

    // C layout: col = n*16 + (lane&15), row = (lane>>4)*4 + j
    #pragma unroll
    for (int n = 0; n < 16; ++n) {
        const int col = n * 16 + lr;
        #pragma unroll
        for (int j = 0; j < 4; ++j)
            Z[(v0 + lg * 4 + j) * 256 + col] = (__bf16)acc[n][j];
    }
}

// ---- edge apply: out[e][o] = sigmoid( Z[src][o] + Z[dst][128+o] ) ----
// 32 lanes per edge, 4 cols per thread. Wave store = 1KB contiguous in ONE
// nt instruction (full lines -> no write amp, no L3 pollution).
__launch_bounds__(256)
__global__ void edge_apply(const __bf16* __restrict__ Z,
                           const int* __restrict__ src_idx,
                           const int* __restrict__ dst_idx,
                           float* __restrict__ out) {
    const int t  = blockIdx.x * 256 + threadIdx.x;
    const int e  = t >> 5;             // 32 lanes per edge
    const int c4 = (t & 31) * 4;       // col group (0,4,...,124)

    const int sv = src_idx[e];         // broadcast across the 32 lanes
    const int dv = dst_idx[e];

    if ((t & 31) == 0) out[ALPHA_OFF + e] = 1.0f;  // softmax(size-1) == 1

    bf16x4 zs = *(const bf16x4*)(Z + sv * 256 + c4);
    bf16x4 zd = *(const bf16x4*)(Z + dv * 256 + 128 + c4);

    f32x4 r;
    #pragma unroll
    for (int j = 0; j < 4; ++j) {
        float x = (float)zs[j] + (float)zd[j];
        r[j] = __builtin_amdgcn_rcpf(1.0f + __expf(-x));
    }
    __builtin_nontemporal_store(r, (f32x4*)(out + e * OUT_FEAT + c4));
}

// ================= FALLBACK PATH (R3, needs only 64 KB ws) =================
__global__ void convert_w_fb(const float* __restrict__ W, __bf16* __restrict__ wl) {
    int gid = blockIdx.x * 256 + threadIdx.x;
    int lane = gid & 63;
    int nk   = gid >> 6;
    int n    = nk & 7;
    int kk   = nk >> 3;
    int row  = n * 16 + (lane & 15);
    int col  = kk * 32 + (lane >> 4) * 8;
    const float* src = W + row * IN_FEAT + col;
    bf16x8 h;
    #pragma unroll
    for (int j = 0; j < 8; ++j) h[j] = (__bf16)src[j];
    *(bf16x8*)(wl + gid * 8) = h;
}

__launch_bounds__(64, 2)
__global__ void edge_kernel_fb(const float* __restrict__ n_f,
                               const __bf16* __restrict__ wl,
                               const int*   __restrict__ src_idx,
                               const int*   __restrict__ dst_idx,
                               float* __restrict__ out) {
    const int lane = threadIdx.x;
    const int e0   = blockIdx.x * 64;
    const int lr   = lane & 15;
    const int lg   = lane >> 4;

    out[ALPHA_OFF + e0 + lane] = 1.0f;

    int sn[4], dn[4];
    #pragma unroll
    for (int r = 0; r < 4; ++r) {
        const int e = e0 + r * 16 + lr;
        sn[r] = src_idx[e];
        dn[r] = dst_idx[e];
    }
    f32x4 acc[4][8];
    #pragma unroll
    for (int r = 0; r < 4; ++r)
        #pragma unroll
        for (int n = 0; n < 8; ++n) acc[r][n] = (f32x4){0.f, 0.f, 0.f, 0.f};

    #pragma unroll
    for (int kk = 0; kk < 8; ++kk) {
        bf16x8 a[4];
        #pragma unroll
        for (int r = 0; r < 4; ++r) {
            const int node = (kk < 4) ? sn[r] : dn[r];
            const float* ap = n_f + node * D_NODE + (kk & 3) * 32 + lg * 8;
            float4 u0 = *(const float4*)ap;
            float4 u1 = *(const float4*)(ap + 4);
            a[r][0] = (__bf16)u0.x; a[r][1] = (__bf16)u0.y;
            a[r][2] = (__bf16)u0.z; a[r][3] = (__bf16)u0.w;
            a[r][4] = (__bf16)u1.x; a[r][5] = (__bf16)u1.y;
            a[r][6] = (__bf16)u1.z; a[r][7] = (__bf16)u1.w;
        }
        const bf16x8* bp = (const bf16x8*)(wl) + kk * 8 * 64 + lane;
        #pragma unroll
        for (int n = 0; n < 8; ++n) {
            bf16x8 b = bp[n * 64];
            #pragma unroll
            for (int r = 0; r < 4; ++r)
                acc[r][n] = __builtin_amdgcn_mfma_f32_16x16x32_bf16(a[r], b, acc[r][n], 0, 0, 0);
        }
    }
    #pragma unroll
    for (int r = 0; r < 4; ++r) {
        const int ebase = e0 + r * 16 + lg * 4;
        #pragma unroll
        for (int n = 0; n < 8; ++n) {
            const int col = n * 16 + lr;
            #pragma unroll
            for (int j = 0; j < 4; ++j) {
                float x = acc[r][n][j];
                out[(ebase + j) * OUT_FEAT + col] = __builtin_amdgcn_rcpf(1.0f + __expf(-x));
            }
        }
    }
}

extern "C" void kernel_launch(void* const* d_in, const int* in_sizes, int n_in,
                              void* d_out, int out_size, void* d_ws, size_t ws_size,
                              hipStream_t stream) {
    const float* n_f    = (const float*)d_in[0];
    const float* W_edge = (const float*)d_in[1];
    // d_in[2] = W_attn: mathematically dead (softmax over size-1 axis == 1)
    const int* src_idx  = (const int*)d_in[3];
    const int* dst_idx  = (const int*)d_in[4];
    float* out = (float*)d_out;

    const size_t need = 65536 + (size_t)N_NODES * 256 * sizeof(__bf16);  // wl + Z
    if (ws_size >= need) {
        __bf16* wl = (__bf16*)d_ws;                       // 64 KB
        __bf16* Z  = (__bf16*)((char*)d_ws + 65536);      // 25.6 MB
        convert_wcat<<<16, 256, 0, stream>>>(W_edge, wl);
        zgemm<<<N_NODES / 16, 64, 0, stream>>>(n_f, wl, Z);
        edge_apply<<<(E_TOTAL * 32) / 256, 256, 0, stream>>>(Z, src_idx, dst_idx, out);
    } else {
        __bf16* wl = (__bf16*)d_ws;
        convert_w_fb<<<16, 256, 0, stream>>>(W_edge, wl);
        edge_kernel_fb<<<E_TOTAL / 64, 64, 0, stream>>>(n_f, wl, src_idx, dst_idx, out);
    }
}